// Round 15
// baseline (1954.386 us; speedup 1.0000x reference)
//
#include <hip/hip_runtime.h>
#include <stdint.h>

// SpikingQNetwork B=16384 D=512 H=2048 H2=1024 A=8 T=8.
// Fast path: bf16 2-term-split MFMA GEMMs; near-threshold neurons repaired
// with f32 sequential-FMA (BLAS mimicry); spike bits patched via atomicXor.
// R14->R15: step2 BARRIER-FREE: each wave stages its own B slice (64 rows x
// BK=32, dbuf) into a private 16KB LDS region -> no cross-wave LDS sharing ->
// no barriers in the t/K loop. Per-wave counted vmcnt(12) orders gl16 vs
// ds_read. Waves free-run -> VALU-expand of one wave overlaps MFMA of
// another (m114), attacking R14's measured 48/48 lockstep split.

typedef __bf16 bf16;
typedef __attribute__((ext_vector_type(8))) __bf16 bf16x8;
typedef __attribute__((ext_vector_type(4))) float f32x4;

#define CAP1 2097152
#define CAP2 2097152
#define MARGIN 2e-3f     // layer 1
#define MARGIN2 5e-4f    // layer 2

__device__ __forceinline__ void gl16(const void* g, void* l) {
  __builtin_amdgcn_global_load_lds(
      (const __attribute__((address_space(1))) uint32_t*)g,
      (__attribute__((address_space(3))) uint32_t*)l, 16, 0, 0);
}

__device__ __forceinline__ float clampf(float v) {
  return fminf(fmaxf(v, 0.f), 1.f);
}

__device__ __forceinline__ uint32_t expand2(uint32_t b) {
  // 2 spike bits -> 2 packed bf16 (1.0 = 0x3F80)
  return ((b & 1u) ? 0x3F80u : 0u) | ((b & 2u) ? 0x3F800000u : 0u);
}

// ---------------- splits (bf16 hi/lo) -------------------------------------

__global__ void split_x_kernel(const float* __restrict__ x, bf16* __restrict__ Ax) {
  int i = blockIdx.x * 256 + threadIdx.x;   // B*D
  int b = i >> 9, d = i & 511;
  float v = x[i];
  bf16 hi = (bf16)v;
  bf16 lo = (bf16)(v - (float)hi);
  size_t base = (size_t)b * 1024;
  Ax[base + d] = hi;
  Ax[base + 512 + d] = lo;
}

__global__ void split_w1_kernel(const float* __restrict__ W1, bf16* __restrict__ B0,
                                bf16* __restrict__ B1) {
  int i = blockIdx.x * 256 + threadIdx.x;   // H*D
  int r = i >> 9, d = i & 511;
  float v = W1[i];
  bf16 hi = (bf16)v;
  bf16 lo = (bf16)(v - (float)hi);
  size_t base = (size_t)r * 1024;
  B0[base + d] = hi;  B0[base + 512 + d] = lo;   // [w0|w1]
  B1[base + d] = lo;  B1[base + 512 + d] = hi;   // [w1|w0]
}

__global__ void split_w2_kernel(const float* __restrict__ W2, bf16* __restrict__ Wh,
                                bf16* __restrict__ Wl) {
  int i = blockIdx.x * 256 + threadIdx.x;   // H2*H
  float v = W2[i];
  bf16 hi = (bf16)v;
  Wh[i] = hi;
  Wl[i] = (bf16)(v - (float)hi);
}

// -------- GEMM1 + fused LIF1 (ballot-packed, hierarchical flags) ----------

#define SA_OFF  0
#define SB0_OFF 16384
#define SB1_OFF 32768

__global__ __launch_bounds__(256, 2) void gemm1_lif1_kernel(
    const bf16* __restrict__ A, const bf16* __restrict__ B0,
    const bf16* __restrict__ B1, const float* __restrict__ bias,
    const float* __restrict__ beta1p,
    uint32_t* __restrict__ spkbits1, uint2* __restrict__ flag1,
    uint32_t* __restrict__ cnt1)
{
  __shared__ __align__(16) uint8_t lds[49152];
  const int tid = threadIdx.x;
  const int lane = tid & 63;
  const int wave = tid >> 6;
  const int wm = (wave >> 1) * 64, wn = (wave & 1) * 64;
  const size_t brow = (size_t)blockIdx.x * 128;
  const size_t bcol = (size_t)blockIdx.y * 128;
  const int K = 1024;
  const float be = clampf(beta1p[0]);

  const bf16* gA  = A  + brow * K;
  const bf16* gB0 = B0 + bcol * K;
  const bf16* gB1 = B1 + bcol * K;

  f32x4 acc[4][4] = {};

  for (int kk = 0; kk < K; kk += 64) {
#pragma unroll
    for (int q = 0; q < 4; ++q) {
      const int flat = q * 256 + tid;
      const int row = flat >> 3;
      const int s   = flat & 7;
      const int c8  = (s ^ (row & 7)) * 8;   // pre-swizzled source column
      gl16(gA  + (size_t)row * K + kk + c8, lds + SA_OFF  + flat * 16);
      gl16(gB0 + (size_t)row * K + kk + c8, lds + SB0_OFF + flat * 16);
      gl16(gB1 + (size_t)row * K + kk + c8, lds + SB1_OFF + flat * 16);
    }
    asm volatile("s_waitcnt vmcnt(0)" ::: "memory");
    __syncthreads();
#pragma unroll
    for (int ks = 0; ks < 2; ++ks) {
      bf16x8 af[4], b0f[4], b1f[4];
#pragma unroll
      for (int i = 0; i < 4; ++i) {
        const int ra = wm + i * 16 + (lane & 15);
        const int sa = ((ks * 4 + (lane >> 4)) ^ (ra & 7)) * 16;
        af[i]  = *(const bf16x8*)(lds + SA_OFF  + ra * 128 + sa);
        const int rb = wn + i * 16 + (lane & 15);
        const int sb = ((ks * 4 + (lane >> 4)) ^ (rb & 7)) * 16;
        b0f[i] = *(const bf16x8*)(lds + SB0_OFF + rb * 128 + sb);
        b1f[i] = *(const bf16x8*)(lds + SB1_OFF + rb * 128 + sb);
      }
#pragma unroll
      for (int m = 0; m < 4; ++m)
#pragma unroll
        for (int n = 0; n < 4; ++n) {
          acc[m][n] = __builtin_amdgcn_mfma_f32_16x16x32_bf16(af[m], b0f[n], acc[m][n], 0, 0, 0);
          acc[m][n] = __builtin_amdgcn_mfma_f32_16x16x32_bf16(af[m], b1f[n], acc[m][n], 0, 0, 0);
        }
    }
    __syncthreads();
  }

  // LDS reuse: flag list (tiles dead after K-loop's final barrier)
  uint32_t* lcnt  = (uint32_t*)lds;            // [0]
  uint32_t* lbase = (uint32_t*)(lds + 4);      // [1]
  uint2*    llist = (uint2*)(lds + 16);
  const uint32_t CAPL = 3000;
  if (tid == 0) *lcnt = 0;
  __syncthreads();

  // LIF1: element-outer (1 mem/hist live), ballot-packed bit output
  const int rg = lane >> 4;
  const bool writer = (lane & 15) == 0;
  uint16_t* sp16 = (uint16_t*)spkbits1;

#pragma unroll
  for (int m = 0; m < 4; ++m)
#pragma unroll
    for (int n = 0; n < 4; ++n) {
      const int chb = (int)(bcol) + wn + n * 16;   // wave-uniform col base
      const int w32 = chb >> 5, half = (chb >> 4) & 1;
      const float bv = bias[chb + (lane & 15)];
#pragma unroll
      for (int j = 0; j < 4; ++j) {
        const float c = acc[m][n][j] + bv;
        float mem = 0.f; uint32_t hist = 0; bool nearThr = false;
#pragma unroll
        for (int t = 0; t < 8; ++t) {
          float rst = (mem > 1.f) ? 1.f : 0.f;
          mem = be * mem + c - rst;
          uint32_t bit = (mem > 1.f) ? 1u : 0u;
          hist |= bit << t;
          nearThr |= (fabsf(mem - 1.f) < MARGIN);
        }
#pragma unroll
        for (int t = 0; t < 8; ++t) {
          unsigned long long bal = __ballot((hist >> t) & 1u);
          if (writer) {
            uint32_t row = (uint32_t)(brow + wm + m * 16 + rg * 4 + j);
            size_t idx = ((size_t)(t * 64 + w32) * 16384 + row) * 2 + half;
            sp16[idx] = (uint16_t)(bal >> (rg * 16));
          }
        }
        if (nearThr) {
          const uint32_t h = (uint32_t)(chb + (lane & 15));
          const uint32_t b = (uint32_t)(brow + wm + m * 16 + rg * 4 + j);
          uint2 en; en.x = (h << 14) | b; en.y = hist;
          uint32_t pos = atomicAdd(lcnt, 1u);
          if (pos < CAPL) llist[pos] = en;
          else { uint32_t g = atomicAdd(cnt1, 1u); if (g < CAP1) flag1[g] = en; }
        }
      }
    }

  __syncthreads();
  uint32_t ln = *lcnt; if (ln > CAPL) ln = CAPL;
  if (tid == 0) *lbase = atomicAdd(cnt1, ln);
  __syncthreads();
  const uint32_t gb = *lbase;
  for (uint32_t i = tid; i < ln; i += 256) {
    uint32_t g = gb + i;
    if (g < CAP1) flag1[g] = llist[i];
  }
}

// ------- repair1: f32 sequential-FMA (BLAS-order mimicry) redo -------------

__global__ __launch_bounds__(256) void repair1_kernel(
    const float* __restrict__ x, const float* __restrict__ W1,
    const float* __restrict__ b1, const float* __restrict__ beta1p,
    const uint2* __restrict__ flag1, const uint32_t* __restrict__ cnt1,
    uint32_t* __restrict__ spkbits1)
{
  uint32_t n = cnt1[0]; if (n > CAP1) n = CAP1;
  const float be = clampf(beta1p[0]);
  for (uint32_t i = blockIdx.x * 256 + threadIdx.x; i < n; i += gridDim.x * 256) {
    uint2 e = flag1[i];
    int h = e.x >> 14, b = e.x & 16383;
    const float* xr = x + (size_t)b * 512;
    const float* wr = W1 + (size_t)h * 512;
    float s = 0.f;                       // sgemm: sequential ascending-k FMA
    for (int d = 0; d < 512; ++d) s = fmaf(xr[d], wr[d], s);
    s = __fadd_rn(s, b1[h]);
    float m = 0.f; uint32_t eb = 0;
#pragma unroll
    for (int t = 0; t < 8; ++t) {
      float rst = (__fsub_rn(m, 1.f) > 0.f) ? 1.f : 0.f;
      m = __fsub_rn(__fadd_rn(__fmul_rn(be, m), s), rst);
      if (__fsub_rn(m, 1.f) > 0.f) eb |= 1u << t;
    }
    uint32_t diff = eb ^ (e.y & 0xFFu);
    if (diff) {
#pragma unroll
      for (int t = 0; t < 8; ++t)
        if ((diff >> t) & 1u)
          atomicXor(&spkbits1[((size_t)t * 64 + (h >> 5)) * 16384 + b], 1u << (h & 31));
    }
  }
}

// ------- step2: barrier-free GEMM + LIF2 (wave-private B staging) ----------

__global__ __launch_bounds__(256, 2) void step2_kernel(
    const uint32_t* __restrict__ spkbits1,
    const bf16* __restrict__ W2h, const bf16* __restrict__ W2l,
    const float* __restrict__ b2, const float* __restrict__ beta2p,
    uint32_t* __restrict__ spkbits2, uint32_t* __restrict__ flag2,
    uint32_t* __restrict__ cnt2)
{
  __shared__ __align__(16) uint8_t lds[65536];   // 4 waves x 16KB private
  const int K = 2048;
  const int tid = threadIdx.x;
  const int lane = tid & 63;
  const int wave = tid >> 6;
  const int wm = (wave >> 1) * 64, wn = (wave & 1) * 64;
  const size_t brow = (size_t)blockIdx.x * 128;
  const size_t bcol = (size_t)blockIdx.y * 128;
  const float be2 = clampf(beta2p[0]);

  const bf16* gB0 = W2h + bcol * K;
  const bf16* gB1 = W2l + bcol * K;
  uint8_t* wlds = lds + wave * 16384;   // private: 2 dbuf x (B0 4KB + B1 4KB)

  float b2c[4];
#pragma unroll
  for (int n = 0; n < 4; ++n) b2c[n] = b2[bcol + wn + n * 16 + (lane & 15)];

  const int rg = lane >> 4;
  const int lnlo = lane & 15;
  const int sh8 = rg * 8;
  const bool writer = lnlo == 0;
  uint16_t* sp16 = (uint16_t*)spkbits2;

  f32x4 acc[4][4] = {};       // mem2, persistent across t
  unsigned long long flg = 0;

  // stage this wave's B slice (rows wn..wn+63, 32 k-cols) into buffer D.
  // dest is linear (base + lane*16); source pre-swizzled: slot s holds
  // k-group (s ^ ((row>>1)&3)) -> read slot rg^((row>>1)&3). 8 gl16/chunk.
#define STAGE_W(D, KC)                                                        \
  {                                                                           \
    _Pragma("unroll")                                                         \
    for (int q = 0; q < 4; ++q) {                                             \
      const int rl = q * 16 + (lane >> 2);                                    \
      const int s = lane & 3;                                                 \
      const int c8 = (s ^ ((rl >> 1) & 3)) * 8;                               \
      gl16(gB0 + (size_t)(wn + rl) * K + (KC) * 32 + c8,                      \
           wlds + (D) * 8192 + q * 1024 + lane * 16);                         \
      gl16(gB1 + (size_t)(wn + rl) * K + (KC) * 32 + c8,                      \
           wlds + (D) * 8192 + 4096 + q * 1024 + lane * 16);                  \
    }                                                                         \
  }

#define LOAD_A(AW, TT, KC)                                                    \
  {                                                                           \
    const uint32_t* pA =                                                      \
        spkbits1 + ((size_t)((TT) * 64 + (KC))) * 16384 + brow;               \
    _Pragma("unroll")                                                         \
    for (int i = 0; i < 4; ++i) AW[i] = pA[wm + i * 16 + lnlo];               \
  }

  // one BK=32 chunk, NO barriers: prefetch next A (4 loads) + stage next B
  // (8 gl16), expand cur A in regs, per-wave vmcnt(12) (= all prev-chunk ops
  // done, this chunk's 12 in flight), ds_read own region, 32 MFMA.
#define CHUNK(CUR, NXT, TT_N, KC_N, D)                                        \
  {                                                                           \
    LOAD_A(NXT, TT_N, KC_N);                                                  \
    STAGE_W((D) ^ 1, KC_N);                                                   \
    bf16x8 af[4];                                                             \
    _Pragma("unroll")                                                         \
    for (int i = 0; i < 4; ++i) {                                             \
      uint32_t byte = (CUR[i] >> sh8) & 0xFFu;                                \
      uint4 u;                                                                \
      u.x = expand2(byte);                                                    \
      u.y = expand2(byte >> 2);                                               \
      u.z = expand2(byte >> 4);                                               \
      u.w = expand2(byte >> 6);                                               \
      af[i] = *(bf16x8*)&u;                                                   \
    }                                                                         \
    asm volatile("s_waitcnt vmcnt(12)" ::: "memory");                         \
    __builtin_amdgcn_s_setprio(1);                                            \
    bf16x8 b0f[4], b1f[4];                                                    \
    _Pragma("unroll")                                                         \
    for (int i = 0; i < 4; ++i) {                                             \
      const int rbl = i * 16 + lnlo;                                          \
      const int sb = (rg ^ ((rbl >> 1) & 3)) * 16;                            \
      b0f[i] = *(const bf16x8*)(wlds + (D) * 8192 + rbl * 64 + sb);           \
      b1f[i] = *(const bf16x8*)(wlds + (D) * 8192 + 4096 + rbl * 64 + sb);    \
    }                                                                         \
    _Pragma("unroll")                                                         \
    for (int m = 0; m < 4; ++m)                                               \
      _Pragma("unroll")                                                       \
      for (int n = 0; n < 4; ++n) {                                           \
        acc[m][n] = __builtin_amdgcn_mfma_f32_16x16x32_bf16(                  \
            af[m], b0f[n], acc[m][n], 0, 0, 0);                               \
        acc[m][n] = __builtin_amdgcn_mfma_f32_16x16x32_bf16(                  \
            af[m], b1f[n], acc[m][n], 0, 0, 0);                               \
      }                                                                       \
    __builtin_amdgcn_s_setprio(0);                                            \
  }

  uint32_t awA[4], awB[4];

  // prologue: prefetch A(t=0,kc=0), stage B(kc=0) into buf 0 (12 vmem ops)
  LOAD_A(awA, 0, 0);
  STAGE_W(0, 0);

  for (int t = 0; t < 8; ++t) {
    // LIF2 pre-update: acc = be2*acc + b2 - reset(prev)   (per-wave)
#pragma unroll
    for (int m = 0; m < 4; ++m)
#pragma unroll
      for (int n = 0; n < 4; ++n)
#pragma unroll
        for (int j = 0; j < 4; ++j) {
          float v = acc[m][n][j];
          float rst = (v > 1.f) ? 1.f : 0.f;
          acc[m][n][j] = be2 * v + (b2c[n] - rst);
        }

#pragma unroll 1
    for (int kc2 = 0; kc2 < 32; ++kc2) {
      CHUNK(awA, awB, t, 2 * kc2 + 1, 0)
      {
        const int kcn = (2 * kc2 + 2) & 63;
        const int tn = (kc2 == 31 && t < 7) ? t + 1 : t;
        CHUNK(awB, awA, tn, kcn, 1)
      }
    }

    // spike bits via ballot (per-wave; no barriers)
#pragma unroll
    for (int m = 0; m < 4; ++m)
#pragma unroll
      for (int n = 0; n < 4; ++n) {
        const int chb = (int)(bcol) + wn + n * 16;
        const int w32 = chb >> 5, half = (chb >> 4) & 1;
#pragma unroll
        for (int j = 0; j < 4; ++j) {
          float v = acc[m][n][j];
          if (fabsf(v - 1.f) < MARGIN2) flg |= 1ull << (m * 16 + n * 4 + j);
          unsigned long long bal = __ballot(v > 1.f);
          if (writer) {
            uint32_t row = (uint32_t)(brow + wm + m * 16 + rg * 4 + j);
            size_t idx = ((size_t)(t * 32 + w32) * 16384 + row) * 2 + half;
            sp16[idx] = (uint16_t)(bal >> (rg * 16));
          }
        }
      }
  }

  // drain in-flight tail staging before reusing LDS, then flag collection
  asm volatile("s_waitcnt vmcnt(0)" ::: "memory");
  __syncthreads();
  uint32_t* lcnt  = (uint32_t*)lds;
  uint32_t* lbase = (uint32_t*)(lds + 4);
  uint32_t* llist = (uint32_t*)(lds + 16);
  const uint32_t CAPL = 6000;
  if (tid == 0) *lcnt = 0;
  __syncthreads();

  if (flg) {
#pragma unroll
    for (int m = 0; m < 4; ++m)
#pragma unroll
      for (int n = 0; n < 4; ++n)
#pragma unroll
        for (int j = 0; j < 4; ++j)
          if ((flg >> (m * 16 + n * 4 + j)) & 1ull) {
            const int row = wm + m * 16 + rg * 4 + j;
            const int col = wn + n * 16 + lnlo;
            uint32_t en = (uint32_t)(((brow + row) << 10) | (bcol + col));
            uint32_t pos = atomicAdd(lcnt, 1u);
            if (pos < CAPL) llist[pos] = en;
            else { uint32_t g = atomicAdd(cnt2, 1u); if (g < CAP2) flag2[g] = en; }
          }
  }

  __syncthreads();
  uint32_t ln = *lcnt; if (ln > CAPL) ln = CAPL;
  if (tid == 0) *lbase = atomicAdd(cnt2, ln);
  __syncthreads();
  const uint32_t gb = *lbase;
  for (uint32_t i = tid; i < ln; i += 256) {
    uint32_t g = gb + i;
    if (g < CAP2) flag2[g] = llist[i];
  }
#undef STAGE_W
#undef LOAD_A
#undef CHUNK
}

// ------- repair2: f32 sequential-sum mimicry, ILP-8 predicated loop --------

__global__ __launch_bounds__(256) void repair2_kernel(
    const uint32_t* __restrict__ spkbits1, const float* __restrict__ W2,
    const float* __restrict__ b2, const float* __restrict__ beta2p,
    const uint32_t* __restrict__ flag2, const uint32_t* __restrict__ cnt2,
    uint32_t* __restrict__ spkbits2)
{
  uint32_t n = cnt2[0]; if (n > CAP2) n = CAP2;
  const float be = clampf(beta2p[0]);
  for (uint32_t i = blockIdx.x * 256 + threadIdx.x; i < n; i += gridDim.x * 256) {
    uint32_t e = flag2[i];
    int b = e >> 10, h2 = e & 1023;
    const float* wr = W2 + (size_t)h2 * 2048;
    const float bias = b2[h2];
    float s[8] = {0, 0, 0, 0, 0, 0, 0, 0};
    for (int w = 0; w < 64; ++w) {
      uint32_t bt[8];
#pragma unroll
      for (int t = 0; t < 8; ++t)
        bt[t] = spkbits1[((size_t)t * 64 + w) * 16384 + b];
#pragma unroll 8
      for (int k = 0; k < 32; ++k) {
        const float wv = wr[w * 32 + k];
#pragma unroll
        for (int t = 0; t < 8; ++t) {
          float addend = ((bt[t] >> k) & 1u) ? wv : 0.0f;
          s[t] = __fadd_rn(s[t], addend);
        }
      }
    }
    float m = 0.f;
#pragma unroll
    for (int t = 0; t < 8; ++t) {
      float st = __fadd_rn(s[t], bias);
      float rst = (__fsub_rn(m, 1.f) > 0.f) ? 1.f : 0.f;
      m = __fsub_rn(__fadd_rn(__fmul_rn(be, m), st), rst);
      uint32_t exact = (__fsub_rn(m, 1.f) > 0.f) ? 1u : 0u;
      uint32_t* wp = &spkbits2[((size_t)t * 32 + (h2 >> 5)) * 16384 + b];
      uint32_t stored = (*wp >> (h2 & 31)) & 1u;
      if (stored != exact) atomicXor(wp, 1u << (h2 & 31));
    }
  }
}

// -------- output: f32 (a,slice) lane split + 3-level shfl reduce -----------

__global__ __launch_bounds__(256) void out_kernel(
    const uint32_t* __restrict__ spkbits2, const float* __restrict__ Wo,
    const float* __restrict__ bo, const float* __restrict__ betaop,
    float* __restrict__ out)
{
  const int wave = threadIdx.x >> 6, lane = threadIdx.x & 63;
  const int b = blockIdx.x * 4 + wave;
  const float beo = clampf(betaop[0]);
  const int a = lane & 7;        // output unit
  const int slice = lane >> 3;   // 128-wide h2 slice

  float s[8] = {0, 0, 0, 0, 0, 0, 0, 0};   // per-t partial sums
#pragma unroll
  for (int q = 0; q < 4; ++q) {
    const int wrd = slice * 4 + q;
    uint32_t wt[8];
#pragma unroll
    for (int t = 0; t < 8; ++t)
      wt[t] = spkbits2[((size_t)(t * 32 + wrd)) * 16384 + b];
    const float* wop = Wo + (size_t)a * 1024 + wrd * 32;
#pragma unroll
    for (int k8 = 0; k8 < 8; ++k8) {
      const float4 wv = *(const float4*)(wop + k8 * 4);
      const float wa[4] = {wv.x, wv.y, wv.z, wv.w};
#pragma unroll
      for (int kk = 0; kk < 4; ++kk) {
        const int k = k8 * 4 + kk;
#pragma unroll
        for (int t = 0; t < 8; ++t)
          s[t] += ((wt[t] >> k) & 1u) ? wa[kk] : 0.0f;
      }
    }
  }
#pragma unroll
  for (int t = 0; t < 8; ++t) {
    s[t] += __shfl_down(s[t], 8, 64);
    s[t] += __shfl_down(s[t], 16, 64);
    s[t] += __shfl_down(s[t], 32, 64);
  }
  if (lane < 8) {
    const float bov = bo[a];
    float mo = 0.f, mx = -1e30f;
#pragma unroll
    for (int t = 0; t < 8; ++t) {
      mo = beo * mo + (s[t] + bov);
      mx = fmaxf(mx, mo);
    }
    out[(size_t)b * 8 + a] = mx;
  }
}

__global__ void zero_hdr_kernel(uint32_t* p) {
  if (threadIdx.x < 64) p[threadIdx.x] = 0;
}

__global__ void fill_sentinel(float* out, int n, float v) {
  int i = blockIdx.x * 256 + threadIdx.x;
  if (i < n) out[i] = v;
}

// ---------------- launch ----------------

extern "C" void kernel_launch(void* const* d_in, const int* in_sizes, int n_in,
                              void* d_out, int out_size, void* d_ws, size_t ws_size,
                              hipStream_t stream)
{
  (void)in_sizes; (void)n_in;
  const float* x   = (const float*)d_in[0];
  const float* W1  = (const float*)d_in[1];
  const float* b1  = (const float*)d_in[2];
  const float* W2  = (const float*)d_in[3];
  const float* b2  = (const float*)d_in[4];
  const float* Wo  = (const float*)d_in[5];
  const float* bo  = (const float*)d_in[6];
  const float* be1 = (const float*)d_in[7];
  const float* be2 = (const float*)d_in[8];
  const float* beo = (const float*)d_in[9];
  float* out = (float*)d_out;

  const int B = 16384, D = 512, H = 2048, H2 = 1024;

  const size_t sz_hdr  = 256;
  const size_t sz_Ax   = (size_t)B * 1024 * 2;        // 32 MB
  const size_t sz_W1s  = (size_t)H * 1024 * 2;        // 4 MB each
  const size_t sz_W2s  = (size_t)H2 * H * 2;          // 4 MB each
  const size_t sz_b1   = (size_t)8 * 64 * B * 4;      // 32 MB
  const size_t sz_b2   = (size_t)8 * 32 * B * 4;      // 16 MB
  const size_t sz_f1   = (size_t)CAP1 * 8;            // 16 MB
  const size_t sz_f2   = (size_t)CAP2 * 4;            // 8 MB
  const size_t need = sz_hdr + sz_Ax + 2 * sz_W1s + 2 * sz_W2s +
                      sz_b1 + sz_b2 + sz_f1 + sz_f2;  // ~120 MB

  if (ws_size < need) {
    fill_sentinel<<<(out_size + 255) / 256, 256, 0, stream>>>(
        out, out_size, 1000.0f + (float)(ws_size >> 20));
    return;
  }

  uint8_t* p = (uint8_t*)d_ws;
  uint32_t* hdr = (uint32_t*)p;     p += sz_hdr;
  bf16* Ax      = (bf16*)p;         p += sz_Ax;
  bf16* W1B0    = (bf16*)p;         p += sz_W1s;
  bf16* W1B1    = (bf16*)p;         p += sz_W1s;
  bf16* W2h     = (bf16*)p;         p += sz_W2s;
  bf16* W2l     = (bf16*)p;         p += sz_W2s;
  uint32_t* spkbits1 = (uint32_t*)p; p += sz_b1;
  uint32_t* spkbits2 = (uint32_t*)p; p += sz_b2;
  uint2* flag1  = (uint2*)p;        p += sz_f1;
  uint32_t* flag2 = (uint32_t*)p;   p += sz_f2;
  uint32_t* cnt1 = hdr + 0;
  uint32_t* cnt2 = hdr + 1;

  zero_hdr_kernel<<<1, 64, 0, stream>>>(hdr);
  split_x_kernel <<<(B * D) / 256, 256, 0, stream>>>(x, Ax);
  split_w1_kernel<<<(H * D) / 256, 256, 0, stream>>>(W1, W1B0, W1B1);
  split_w2_kernel<<<(H2 * H) / 256, 256, 0, stream>>>(W2, W2h, W2l);

  gemm1_lif1_kernel<<<dim3(B / 128, H / 128), 256, 0, stream>>>(
      Ax, W1B0, W1B1, b1, be1, spkbits1, flag1, cnt1);
  repair1_kernel<<<256, 256, 0, stream>>>(x, W1, b1, be1, flag1, cnt1, spkbits1);

  step2_kernel<<<dim3(B / 128, H2 / 128), 256, 0, stream>>>(
      spkbits1, W2h, W2l, b2, be2, spkbits2, flag2, cnt2);
  repair2_kernel<<<256, 256, 0, stream>>>(spkbits1, W2, b2, be2, flag2, cnt2, spkbits2);

  out_kernel<<<B / 4, 256, 0, stream>>>(spkbits2, Wo, bo, beo, out);
}

// Round 16
// 1708.866 us; speedup vs baseline: 1.1437x; 1.1437x over previous
//
#include <hip/hip_runtime.h>
#include <stdint.h>

// SpikingQNetwork B=16384 D=512 H=2048 H2=1024 A=8 T=8.
// Fast path: bf16 2-term-split MFMA GEMMs; near-threshold neurons repaired
// with f32 sequential-FMA (BLAS mimicry); spike bits patched via atomicXor.
// R15->R16: REVERT to R11's session-best step2 (2-phase BK=64 dbuf, counted
// vmcnt(8), (256,2), no setprio). Five structural variants (R10 deep-unroll,
// R12/R13 BK=32, R14 +setprio, R15 barrier-free) all regressed or were null;
// R11 = 1710us total, step2 1010us, is the measured optimum of this family.

typedef __bf16 bf16;
typedef __attribute__((ext_vector_type(8))) __bf16 bf16x8;
typedef __attribute__((ext_vector_type(4))) float f32x4;

#define CAP1 2097152
#define CAP2 2097152
#define MARGIN 2e-3f     // layer 1
#define MARGIN2 5e-4f    // layer 2

__device__ __forceinline__ void gl16(const void* g, void* l) {
  __builtin_amdgcn_global_load_lds(
      (const __attribute__((address_space(1))) uint32_t*)g,
      (__attribute__((address_space(3))) uint32_t*)l, 16, 0, 0);
}

__device__ __forceinline__ float clampf(float v) {
  return fminf(fmaxf(v, 0.f), 1.f);
}

__device__ __forceinline__ uint32_t expand2(uint32_t b) {
  // 2 spike bits -> 2 packed bf16 (1.0 = 0x3F80)
  return ((b & 1u) ? 0x3F80u : 0u) | ((b & 2u) ? 0x3F800000u : 0u);
}

// ---------------- splits (bf16 hi/lo) -------------------------------------

__global__ void split_x_kernel(const float* __restrict__ x, bf16* __restrict__ Ax) {
  int i = blockIdx.x * 256 + threadIdx.x;   // B*D
  int b = i >> 9, d = i & 511;
  float v = x[i];
  bf16 hi = (bf16)v;
  bf16 lo = (bf16)(v - (float)hi);
  size_t base = (size_t)b * 1024;
  Ax[base + d] = hi;
  Ax[base + 512 + d] = lo;
}

__global__ void split_w1_kernel(const float* __restrict__ W1, bf16* __restrict__ B0,
                                bf16* __restrict__ B1) {
  int i = blockIdx.x * 256 + threadIdx.x;   // H*D
  int r = i >> 9, d = i & 511;
  float v = W1[i];
  bf16 hi = (bf16)v;
  bf16 lo = (bf16)(v - (float)hi);
  size_t base = (size_t)r * 1024;
  B0[base + d] = hi;  B0[base + 512 + d] = lo;   // [w0|w1]
  B1[base + d] = lo;  B1[base + 512 + d] = hi;   // [w1|w0]
}

__global__ void split_w2_kernel(const float* __restrict__ W2, bf16* __restrict__ Wh,
                                bf16* __restrict__ Wl) {
  int i = blockIdx.x * 256 + threadIdx.x;   // H2*H
  float v = W2[i];
  bf16 hi = (bf16)v;
  Wh[i] = hi;
  Wl[i] = (bf16)(v - (float)hi);
}

// -------- GEMM1 + fused LIF1 (ballot-packed, hierarchical flags) ----------

#define SA_OFF  0
#define SB0_OFF 16384
#define SB1_OFF 32768

__global__ __launch_bounds__(256, 2) void gemm1_lif1_kernel(
    const bf16* __restrict__ A, const bf16* __restrict__ B0,
    const bf16* __restrict__ B1, const float* __restrict__ bias,
    const float* __restrict__ beta1p,
    uint32_t* __restrict__ spkbits1, uint2* __restrict__ flag1,
    uint32_t* __restrict__ cnt1)
{
  __shared__ __align__(16) uint8_t lds[49152];
  const int tid = threadIdx.x;
  const int lane = tid & 63;
  const int wave = tid >> 6;
  const int wm = (wave >> 1) * 64, wn = (wave & 1) * 64;
  const size_t brow = (size_t)blockIdx.x * 128;
  const size_t bcol = (size_t)blockIdx.y * 128;
  const int K = 1024;
  const float be = clampf(beta1p[0]);

  const bf16* gA  = A  + brow * K;
  const bf16* gB0 = B0 + bcol * K;
  const bf16* gB1 = B1 + bcol * K;

  f32x4 acc[4][4] = {};

  for (int kk = 0; kk < K; kk += 64) {
#pragma unroll
    for (int q = 0; q < 4; ++q) {
      const int flat = q * 256 + tid;
      const int row = flat >> 3;
      const int s   = flat & 7;
      const int c8  = (s ^ (row & 7)) * 8;   // pre-swizzled source column
      gl16(gA  + (size_t)row * K + kk + c8, lds + SA_OFF  + flat * 16);
      gl16(gB0 + (size_t)row * K + kk + c8, lds + SB0_OFF + flat * 16);
      gl16(gB1 + (size_t)row * K + kk + c8, lds + SB1_OFF + flat * 16);
    }
    asm volatile("s_waitcnt vmcnt(0)" ::: "memory");
    __syncthreads();
#pragma unroll
    for (int ks = 0; ks < 2; ++ks) {
      bf16x8 af[4], b0f[4], b1f[4];
#pragma unroll
      for (int i = 0; i < 4; ++i) {
        const int ra = wm + i * 16 + (lane & 15);
        const int sa = ((ks * 4 + (lane >> 4)) ^ (ra & 7)) * 16;
        af[i]  = *(const bf16x8*)(lds + SA_OFF  + ra * 128 + sa);
        const int rb = wn + i * 16 + (lane & 15);
        const int sb = ((ks * 4 + (lane >> 4)) ^ (rb & 7)) * 16;
        b0f[i] = *(const bf16x8*)(lds + SB0_OFF + rb * 128 + sb);
        b1f[i] = *(const bf16x8*)(lds + SB1_OFF + rb * 128 + sb);
      }
#pragma unroll
      for (int m = 0; m < 4; ++m)
#pragma unroll
        for (int n = 0; n < 4; ++n) {
          acc[m][n] = __builtin_amdgcn_mfma_f32_16x16x32_bf16(af[m], b0f[n], acc[m][n], 0, 0, 0);
          acc[m][n] = __builtin_amdgcn_mfma_f32_16x16x32_bf16(af[m], b1f[n], acc[m][n], 0, 0, 0);
        }
    }
    __syncthreads();
  }

  // LDS reuse: flag list (tiles dead after K-loop's final barrier)
  uint32_t* lcnt  = (uint32_t*)lds;            // [0]
  uint32_t* lbase = (uint32_t*)(lds + 4);      // [1]
  uint2*    llist = (uint2*)(lds + 16);
  const uint32_t CAPL = 3000;
  if (tid == 0) *lcnt = 0;
  __syncthreads();

  // LIF1: element-outer (1 mem/hist live), ballot-packed bit output
  const int rg = lane >> 4;
  const bool writer = (lane & 15) == 0;
  uint16_t* sp16 = (uint16_t*)spkbits1;

#pragma unroll
  for (int m = 0; m < 4; ++m)
#pragma unroll
    for (int n = 0; n < 4; ++n) {
      const int chb = (int)(bcol) + wn + n * 16;   // wave-uniform col base
      const int w32 = chb >> 5, half = (chb >> 4) & 1;
      const float bv = bias[chb + (lane & 15)];
#pragma unroll
      for (int j = 0; j < 4; ++j) {
        const float c = acc[m][n][j] + bv;
        float mem = 0.f; uint32_t hist = 0; bool nearThr = false;
#pragma unroll
        for (int t = 0; t < 8; ++t) {
          float rst = (mem > 1.f) ? 1.f : 0.f;
          mem = be * mem + c - rst;
          uint32_t bit = (mem > 1.f) ? 1u : 0u;
          hist |= bit << t;
          nearThr |= (fabsf(mem - 1.f) < MARGIN);
        }
#pragma unroll
        for (int t = 0; t < 8; ++t) {
          unsigned long long bal = __ballot((hist >> t) & 1u);
          if (writer) {
            uint32_t row = (uint32_t)(brow + wm + m * 16 + rg * 4 + j);
            size_t idx = ((size_t)(t * 64 + w32) * 16384 + row) * 2 + half;
            sp16[idx] = (uint16_t)(bal >> (rg * 16));
          }
        }
        if (nearThr) {
          const uint32_t h = (uint32_t)(chb + (lane & 15));
          const uint32_t b = (uint32_t)(brow + wm + m * 16 + rg * 4 + j);
          uint2 en; en.x = (h << 14) | b; en.y = hist;
          uint32_t pos = atomicAdd(lcnt, 1u);
          if (pos < CAPL) llist[pos] = en;
          else { uint32_t g = atomicAdd(cnt1, 1u); if (g < CAP1) flag1[g] = en; }
        }
      }
    }

  __syncthreads();
  uint32_t ln = *lcnt; if (ln > CAPL) ln = CAPL;
  if (tid == 0) *lbase = atomicAdd(cnt1, ln);
  __syncthreads();
  const uint32_t gb = *lbase;
  for (uint32_t i = tid; i < ln; i += 256) {
    uint32_t g = gb + i;
    if (g < CAP1) flag1[g] = llist[i];
  }
}

// ------- repair1: f32 sequential-FMA (BLAS-order mimicry) redo -------------

__global__ __launch_bounds__(256) void repair1_kernel(
    const float* __restrict__ x, const float* __restrict__ W1,
    const float* __restrict__ b1, const float* __restrict__ beta1p,
    const uint2* __restrict__ flag1, const uint32_t* __restrict__ cnt1,
    uint32_t* __restrict__ spkbits1)
{
  uint32_t n = cnt1[0]; if (n > CAP1) n = CAP1;
  const float be = clampf(beta1p[0]);
  for (uint32_t i = blockIdx.x * 256 + threadIdx.x; i < n; i += gridDim.x * 256) {
    uint2 e = flag1[i];
    int h = e.x >> 14, b = e.x & 16383;
    const float* xr = x + (size_t)b * 512;
    const float* wr = W1 + (size_t)h * 512;
    float s = 0.f;                       // sgemm: sequential ascending-k FMA
    for (int d = 0; d < 512; ++d) s = fmaf(xr[d], wr[d], s);
    s = __fadd_rn(s, b1[h]);
    float m = 0.f; uint32_t eb = 0;
#pragma unroll
    for (int t = 0; t < 8; ++t) {
      float rst = (__fsub_rn(m, 1.f) > 0.f) ? 1.f : 0.f;
      m = __fsub_rn(__fadd_rn(__fmul_rn(be, m), s), rst);
      if (__fsub_rn(m, 1.f) > 0.f) eb |= 1u << t;
    }
    uint32_t diff = eb ^ (e.y & 0xFFu);
    if (diff) {
#pragma unroll
      for (int t = 0; t < 8; ++t)
        if ((diff >> t) & 1u)
          atomicXor(&spkbits1[((size_t)t * 64 + (h >> 5)) * 16384 + b], 1u << (h & 31));
    }
  }
}

// ------- step2: 2-phase pipelined GEMM + LIF2 (reg-A, B dbuf 64KB) ---------

#define BOFF(d) ((d) * 32768)

__global__ __launch_bounds__(256, 2) void step2_kernel(
    const uint32_t* __restrict__ spkbits1,
    const bf16* __restrict__ W2h, const bf16* __restrict__ W2l,
    const float* __restrict__ b2, const float* __restrict__ beta2p,
    uint32_t* __restrict__ spkbits2, uint32_t* __restrict__ flag2,
    uint32_t* __restrict__ cnt2)
{
  __shared__ __align__(16) uint8_t lds[65536];   // 2 x (B0 16KB + B1 16KB)
  const int K = 2048;
  const int tid = threadIdx.x;
  const int lane = tid & 63;
  const int wave = tid >> 6;
  const int wm = (wave >> 1) * 64, wn = (wave & 1) * 64;
  const size_t brow = (size_t)blockIdx.x * 128;
  const size_t bcol = (size_t)blockIdx.y * 128;
  const float be2 = clampf(beta2p[0]);

  const bf16* gB0 = W2h + bcol * K;
  const bf16* gB1 = W2l + bcol * K;

  float b2c[4];
#pragma unroll
  for (int n = 0; n < 4; ++n) b2c[n] = b2[bcol + wn + n * 16 + (lane & 15)];

  const int rg = lane >> 4;
  const int lnlo = lane & 15;
  const int sh8 = rg * 8;
  const bool writer = lnlo == 0;
  uint16_t* sp16 = (uint16_t*)spkbits2;

  f32x4 acc[4][4] = {};       // mem2, persistent across t
  unsigned long long flg = 0;

#define STAGE_B(D, KKN)                                                       \
  {                                                                           \
    _Pragma("unroll")                                                         \
    for (int q = 0; q < 4; ++q) {                                             \
      const int flat = q * 256 + tid;                                         \
      const int row = flat >> 3;                                              \
      const int s = flat & 7;                                                 \
      const int c8 = (s ^ (row & 7)) * 8;                                     \
      gl16(gB0 + (size_t)row * K + (KKN) * 64 + c8, lds + BOFF(D) + flat * 16);\
      gl16(gB1 + (size_t)row * K + (KKN) * 64 + c8,                           \
           lds + BOFF(D) + 16384 + flat * 16);                                \
    }                                                                         \
  }

  // One chunk: load A-words (8/lane), stage next-B into other buffer,
  // expand A in regs, counted vmcnt (cur-B done, next-B in flight),
  // barrier, MFMA from sB[D], barrier.
#define CHUNK(KK, NK, D)                                                      \
  {                                                                           \
    uint32_t aw[2][4];                                                        \
    const uint32_t* pA =                                                      \
        spkbits1 + ((size_t)(t * 64 + (KK) * 2)) * 16384 + brow;              \
    _Pragma("unroll")                                                         \
    for (int ks = 0; ks < 2; ++ks)                                            \
      _Pragma("unroll")                                                       \
      for (int i = 0; i < 4; ++i)                                             \
        aw[ks][i] = pA[(size_t)ks * 16384 + wm + i * 16 + lnlo];              \
    STAGE_B(D ^ 1, NK);                                                       \
    bf16x8 af[2][4];                                                          \
    _Pragma("unroll")                                                         \
    for (int ks = 0; ks < 2; ++ks)                                            \
      _Pragma("unroll")                                                       \
      for (int i = 0; i < 4; ++i) {                                           \
        uint32_t byte = (aw[ks][i] >> sh8) & 0xFFu;                           \
        uint4 u;                                                              \
        u.x = expand2(byte);                                                  \
        u.y = expand2(byte >> 2);                                             \
        u.z = expand2(byte >> 4);                                             \
        u.w = expand2(byte >> 6);                                             \
        af[ks][i] = *(bf16x8*)&u;                                             \
      }                                                                       \
    asm volatile("s_waitcnt vmcnt(8)" ::: "memory");                          \
    __builtin_amdgcn_s_barrier();                                             \
    _Pragma("unroll")                                                         \
    for (int ks = 0; ks < 2; ++ks) {                                          \
      bf16x8 b0f[4], b1f[4];                                                  \
      _Pragma("unroll")                                                       \
      for (int i = 0; i < 4; ++i) {                                           \
        const int rb = wn + i * 16 + lnlo;                                    \
        const int sb = ((ks * 4 + rg) ^ (rb & 7)) * 16;                       \
        b0f[i] = *(const bf16x8*)(lds + BOFF(D) + rb * 128 + sb);             \
        b1f[i] = *(const bf16x8*)(lds + BOFF(D) + 16384 + rb * 128 + sb);     \
      }                                                                       \
      _Pragma("unroll")                                                       \
      for (int m = 0; m < 4; ++m)                                             \
        _Pragma("unroll")                                                     \
        for (int n = 0; n < 4; ++n) {                                         \
          acc[m][n] = __builtin_amdgcn_mfma_f32_16x16x32_bf16(                \
              af[ks][m], b0f[n], acc[m][n], 0, 0, 0);                         \
          acc[m][n] = __builtin_amdgcn_mfma_f32_16x16x32_bf16(                \
              af[ks][m], b1f[n], acc[m][n], 0, 0, 0);                         \
        }                                                                     \
    }                                                                         \
    __builtin_amdgcn_s_barrier();                                             \
  }

  // prologue: stage B(chunk 0) into buf 0
  STAGE_B(0, 0);

  for (int t = 0; t < 8; ++t) {
    // LIF2 pre-update: acc = be2*acc + b2 - reset(prev)
#pragma unroll
    for (int m = 0; m < 4; ++m)
#pragma unroll
      for (int n = 0; n < 4; ++n)
#pragma unroll
        for (int j = 0; j < 4; ++j) {
          float v = acc[m][n][j];
          float rst = (v > 1.f) ? 1.f : 0.f;
          acc[m][n][j] = be2 * v + (b2c[n] - rst);
        }

#pragma unroll 1
    for (int kk2 = 0; kk2 < 16; ++kk2) {
      CHUNK(2 * kk2,     (2 * kk2 + 1) & 31, 0)
      CHUNK(2 * kk2 + 1, (2 * kk2 + 2) & 31, 1)
    }

    // spike bits via ballot (register-only; no LDS)
#pragma unroll
    for (int m = 0; m < 4; ++m)
#pragma unroll
      for (int n = 0; n < 4; ++n) {
        const int chb = (int)(bcol) + wn + n * 16;
        const int w32 = chb >> 5, half = (chb >> 4) & 1;
#pragma unroll
        for (int j = 0; j < 4; ++j) {
          float v = acc[m][n][j];
          if (fabsf(v - 1.f) < MARGIN2) flg |= 1ull << (m * 16 + n * 4 + j);
          unsigned long long bal = __ballot(v > 1.f);
          if (writer) {
            uint32_t row = (uint32_t)(brow + wm + m * 16 + rg * 4 + j);
            size_t idx = ((size_t)(t * 32 + w32) * 16384 + row) * 2 + half;
            sp16[idx] = (uint16_t)(bal >> (rg * 16));
          }
        }
      }
  }

  // hierarchical flag collection (LDS dead; __syncthreads drains mem ops)
  __syncthreads();
  uint32_t* lcnt  = (uint32_t*)lds;
  uint32_t* lbase = (uint32_t*)(lds + 4);
  uint32_t* llist = (uint32_t*)(lds + 16);
  const uint32_t CAPL = 6000;
  if (tid == 0) *lcnt = 0;
  __syncthreads();

  if (flg) {
#pragma unroll
    for (int m = 0; m < 4; ++m)
#pragma unroll
      for (int n = 0; n < 4; ++n)
#pragma unroll
        for (int j = 0; j < 4; ++j)
          if ((flg >> (m * 16 + n * 4 + j)) & 1ull) {
            const int row = wm + m * 16 + rg * 4 + j;
            const int col = wn + n * 16 + lnlo;
            uint32_t en = (uint32_t)(((brow + row) << 10) | (bcol + col));
            uint32_t pos = atomicAdd(lcnt, 1u);
            if (pos < CAPL) llist[pos] = en;
            else { uint32_t g = atomicAdd(cnt2, 1u); if (g < CAP2) flag2[g] = en; }
          }
  }

  __syncthreads();
  uint32_t ln = *lcnt; if (ln > CAPL) ln = CAPL;
  if (tid == 0) *lbase = atomicAdd(cnt2, ln);
  __syncthreads();
  const uint32_t gb = *lbase;
  for (uint32_t i = tid; i < ln; i += 256) {
    uint32_t g = gb + i;
    if (g < CAP2) flag2[g] = llist[i];
  }
#undef STAGE_B
#undef CHUNK
}

// ------- repair2: f32 sequential-sum mimicry, ILP-8 predicated loop --------

__global__ __launch_bounds__(256) void repair2_kernel(
    const uint32_t* __restrict__ spkbits1, const float* __restrict__ W2,
    const float* __restrict__ b2, const float* __restrict__ beta2p,
    const uint32_t* __restrict__ flag2, const uint32_t* __restrict__ cnt2,
    uint32_t* __restrict__ spkbits2)
{
  uint32_t n = cnt2[0]; if (n > CAP2) n = CAP2;
  const float be = clampf(beta2p[0]);
  for (uint32_t i = blockIdx.x * 256 + threadIdx.x; i < n; i += gridDim.x * 256) {
    uint32_t e = flag2[i];
    int b = e >> 10, h2 = e & 1023;
    const float* wr = W2 + (size_t)h2 * 2048;
    const float bias = b2[h2];
    float s[8] = {0, 0, 0, 0, 0, 0, 0, 0};
    for (int w = 0; w < 64; ++w) {
      uint32_t bt[8];
#pragma unroll
      for (int t = 0; t < 8; ++t)
        bt[t] = spkbits1[((size_t)t * 64 + w) * 16384 + b];
#pragma unroll 8
      for (int k = 0; k < 32; ++k) {
        const float wv = wr[w * 32 + k];
#pragma unroll
        for (int t = 0; t < 8; ++t) {
          float addend = ((bt[t] >> k) & 1u) ? wv : 0.0f;
          s[t] = __fadd_rn(s[t], addend);
        }
      }
    }
    float m = 0.f;
#pragma unroll
    for (int t = 0; t < 8; ++t) {
      float st = __fadd_rn(s[t], bias);
      float rst = (__fsub_rn(m, 1.f) > 0.f) ? 1.f : 0.f;
      m = __fsub_rn(__fadd_rn(__fmul_rn(be, m), st), rst);
      uint32_t exact = (__fsub_rn(m, 1.f) > 0.f) ? 1u : 0u;
      uint32_t* wp = &spkbits2[((size_t)t * 32 + (h2 >> 5)) * 16384 + b];
      uint32_t stored = (*wp >> (h2 & 31)) & 1u;
      if (stored != exact) atomicXor(wp, 1u << (h2 & 31));
    }
  }
}

// -------- output: f32 (a,slice) lane split + 3-level shfl reduce -----------

__global__ __launch_bounds__(256) void out_kernel(
    const uint32_t* __restrict__ spkbits2, const float* __restrict__ Wo,
    const float* __restrict__ bo, const float* __restrict__ betaop,
    float* __restrict__ out)
{
  const int wave = threadIdx.x >> 6, lane = threadIdx.x & 63;
  const int b = blockIdx.x * 4 + wave;
  const float beo = clampf(betaop[0]);
  const int a = lane & 7;        // output unit
  const int slice = lane >> 3;   // 128-wide h2 slice

  float s[8] = {0, 0, 0, 0, 0, 0, 0, 0};   // per-t partial sums
#pragma unroll
  for (int q = 0; q < 4; ++q) {
    const int wrd = slice * 4 + q;
    uint32_t wt[8];
#pragma unroll
    for (int t = 0; t < 8; ++t)
      wt[t] = spkbits2[((size_t)(t * 32 + wrd)) * 16384 + b];
    const float* wop = Wo + (size_t)a * 1024 + wrd * 32;
#pragma unroll
    for (int k8 = 0; k8 < 8; ++k8) {
      const float4 wv = *(const float4*)(wop + k8 * 4);
      const float wa[4] = {wv.x, wv.y, wv.z, wv.w};
#pragma unroll
      for (int kk = 0; kk < 4; ++kk) {
        const int k = k8 * 4 + kk;
#pragma unroll
        for (int t = 0; t < 8; ++t)
          s[t] += ((wt[t] >> k) & 1u) ? wa[kk] : 0.0f;
      }
    }
  }
#pragma unroll
  for (int t = 0; t < 8; ++t) {
    s[t] += __shfl_down(s[t], 8, 64);
    s[t] += __shfl_down(s[t], 16, 64);
    s[t] += __shfl_down(s[t], 32, 64);
  }
  if (lane < 8) {
    const float bov = bo[a];
    float mo = 0.f, mx = -1e30f;
#pragma unroll
    for (int t = 0; t < 8; ++t) {
      mo = beo * mo + (s[t] + bov);
      mx = fmaxf(mx, mo);
    }
    out[(size_t)b * 8 + a] = mx;
  }
}

__global__ void zero_hdr_kernel(uint32_t* p) {
  if (threadIdx.x < 64) p[threadIdx.x] = 0;
}

__global__ void fill_sentinel(float* out, int n, float v) {
  int i = blockIdx.x * 256 + threadIdx.x;
  if (i < n) out[i] = v;
}

// ---------------- launch ----------------

extern "C" void kernel_launch(void* const* d_in, const int* in_sizes, int n_in,
                              void* d_out, int out_size, void* d_ws, size_t ws_size,
                              hipStream_t stream)
{
  (void)in_sizes; (void)n_in;
  const float* x   = (const float*)d_in[0];
  const float* W1  = (const float*)d_in[1];
  const float* b1  = (const float*)d_in[2];
  const float* W2  = (const float*)d_in[3];
  const float* b2  = (const float*)d_in[4];
  const float* Wo  = (const float*)d_in[5];
  const float* bo  = (const float*)d_in[6];
  const float* be1 = (const float*)d_in[7];
  const float* be2 = (const float*)d_in[8];
  const float* beo = (const float*)d_in[9];
  float* out = (float*)d_out;

  const int B = 16384, D = 512, H = 2048, H2 = 1024;

  const size_t sz_hdr  = 256;
  const size_t sz_Ax   = (size_t)B * 1024 * 2;        // 32 MB
  const size_t sz_W1s  = (size_t)H * 1024 * 2;        // 4 MB each
  const size_t sz_W2s  = (size_t)H2 * H * 2;          // 4 MB each
  const size_t sz_b1   = (size_t)8 * 64 * B * 4;      // 32 MB
  const size_t sz_b2   = (size_t)8 * 32 * B * 4;      // 16 MB
  const size_t sz_f1   = (size_t)CAP1 * 8;            // 16 MB
  const size_t sz_f2   = (size_t)CAP2 * 4;            // 8 MB
  const size_t need = sz_hdr + sz_Ax + 2 * sz_W1s + 2 * sz_W2s +
                      sz_b1 + sz_b2 + sz_f1 + sz_f2;  // ~120 MB

  if (ws_size < need) {
    fill_sentinel<<<(out_size + 255) / 256, 256, 0, stream>>>(
        out, out_size, 1000.0f + (float)(ws_size >> 20));
    return;
  }

  uint8_t* p = (uint8_t*)d_ws;
  uint32_t* hdr = (uint32_t*)p;     p += sz_hdr;
  bf16* Ax      = (bf16*)p;         p += sz_Ax;
  bf16* W1B0    = (bf16*)p;         p += sz_W1s;
  bf16* W1B1    = (bf16*)p;         p += sz_W1s;
  bf16* W2h     = (bf16*)p;         p += sz_W2s;
  bf16* W2l     = (bf16*)p;         p += sz_W2s;
  uint32_t* spkbits1 = (uint32_t*)p; p += sz_b1;
  uint32_t* spkbits2 = (uint32_t*)p; p += sz_b2;
  uint2* flag1  = (uint2*)p;        p += sz_f1;
  uint32_t* flag2 = (uint32_t*)p;   p += sz_f2;
  uint32_t* cnt1 = hdr + 0;
  uint32_t* cnt2 = hdr + 1;

  zero_hdr_kernel<<<1, 64, 0, stream>>>(hdr);
  split_x_kernel <<<(B * D) / 256, 256, 0, stream>>>(x, Ax);
  split_w1_kernel<<<(H * D) / 256, 256, 0, stream>>>(W1, W1B0, W1B1);
  split_w2_kernel<<<(H2 * H) / 256, 256, 0, stream>>>(W2, W2h, W2l);

  gemm1_lif1_kernel<<<dim3(B / 128, H / 128), 256, 0, stream>>>(
      Ax, W1B0, W1B1, b1, be1, spkbits1, flag1, cnt1);
  repair1_kernel<<<256, 256, 0, stream>>>(x, W1, b1, be1, flag1, cnt1, spkbits1);

  step2_kernel<<<dim3(B / 128, H2 / 128), 256, 0, stream>>>(
      spkbits1, W2h, W2l, b2, be2, spkbits2, flag2, cnt2);
  repair2_kernel<<<256, 256, 0, stream>>>(spkbits1, W2, b2, be2, flag2, cnt2, spkbits2);

  out_kernel<<<B / 4, 256, 0, stream>>>(spkbits2, Wo, bo, beo, out);
}